// Round 4
// baseline (722.941 us; speedup 1.0000x reference)
//
#include <hip/hip_runtime.h>
#include <math.h>

#define BINS 10
#define NBLOCKS 2048
#define THREADS 256

struct Partial {
    float sum[BINS];
    float cnt[BINS];   // counts <= 20608 per block: exact in float
};

// Histogram lives in LDS as per-THREAD private slots: hist[bin*256 + tid] (sums),
// hist[2560 + bin*256 + tid] (counts). atomicAdd(shared float) with unused return
// compiles to no-return ds_add_f32: fire-and-forget, no RMW latency chain.
// Bank = (bin*256 + tid) % 32 = lane % 32 -> 2-way aliasing (free), any bin mix.
__device__ __forceinline__ void accum_one(float x, float t, float w,
                                          float* __restrict__ my) {
    float ax  = __builtin_fabsf(x);
    float e   = __expf(-ax);                      // exp(-|x|) in (0,1]
    float opd = 1.0f + e;
    float inv = __builtin_amdgcn_rcpf(opd);
    float sig = (x >= 0.0f) ? inv : (1.0f - inv); // sigmoid(x)
    float g   = __builtin_fabsf(sig - t);         // in [0,1)
    int   idx = (int)(g * 10.0f);                 // trunc == floor (g >= 0)
    idx = idx > (BINS - 1) ? (BINS - 1) : idx;
    bool valid = (w > 0.0f);
    float bce = fmaxf(x, 0.0f) - x * t + __logf(opd);
    atomicAdd(&my[idx * THREADS],                  valid ? bce : 0.0f);
    atomicAdd(&my[idx * THREADS + BINS * THREADS], valid ? 1.0f : 0.0f);
}

__global__ __launch_bounds__(THREADS) void ghmc_main(const float* __restrict__ pred,
                                                     const float* __restrict__ target,
                                                     const float* __restrict__ lw,
                                                     Partial* __restrict__ part,
                                                     long long total) {
    __shared__ float hist[2 * BINS * THREADS];   // 20480 B -> 8 blocks/CU
    const int tid = threadIdx.x;
    float* my = &hist[tid];

    // zero private slots (no sync needed: slot b*256+tid touched only by thread tid)
#pragma unroll
    for (int b = 0; b < 2 * BINS; ++b) hist[b * THREADS + tid] = 0.0f;

    const long long nvec   = total >> 2;                      // float4 chunks
    const long long stride = (long long)gridDim.x * THREADS;
    const float4* __restrict__ P = reinterpret_cast<const float4*>(pred);
    const float4* __restrict__ T = reinterpret_cast<const float4*>(target);
    const float4* __restrict__ W = reinterpret_cast<const float4*>(lw);

    long long i = (long long)blockIdx.x * THREADS + tid;
    for (; i + stride < nvec; i += 2 * stride) {
        float4 p0 = P[i];          float4 t0 = T[i];          float4 w0 = W[i];
        float4 p1 = P[i + stride]; float4 t1 = T[i + stride]; float4 w1 = W[i + stride];
        accum_one(p0.x, t0.x, w0.x, my);
        accum_one(p0.y, t0.y, w0.y, my);
        accum_one(p0.z, t0.z, w0.z, my);
        accum_one(p0.w, t0.w, w0.w, my);
        accum_one(p1.x, t1.x, w1.x, my);
        accum_one(p1.y, t1.y, w1.y, my);
        accum_one(p1.z, t1.z, w1.z, my);
        accum_one(p1.w, t1.w, w1.w, my);
    }
    for (; i < nvec; i += stride) {
        float4 p = P[i]; float4 t = T[i]; float4 w = W[i];
        accum_one(p.x, t.x, w.x, my);
        accum_one(p.y, t.y, w.y, my);
        accum_one(p.z, t.z, w.z, my);
        accum_one(p.w, t.w, w.w, my);
    }

    // scalar tail (total % 4): block 0 only
    const long long base = nvec << 2;
    const int rem = (int)(total - base);
    if (blockIdx.x == 0 && tid < rem)
        accum_one(pred[base + tid], target[base + tid], lw[base + tid], my);

    __syncthreads();   // drain ds_adds; cross-thread reads next

    // read back own slots, wave butterfly, cross-wave via reused LDS
    float s[BINS], c[BINS];
#pragma unroll
    for (int b = 0; b < BINS; ++b) {
        s[b] = hist[b * THREADS + tid];
        c[b] = hist[b * THREADS + tid + BINS * THREADS];
    }
#pragma unroll
    for (int b = 0; b < BINS; ++b) {
#pragma unroll
        for (int off = 32; off; off >>= 1) {
            s[b] += __shfl_xor(s[b], off, 64);
            c[b] += __shfl_xor(c[b], off, 64);
        }
    }
    __syncthreads();   // everyone done reading hist; reuse as staging
    const int wid  = tid >> 6;
    const int lane = tid & 63;
    if (lane == 0) {
#pragma unroll
        for (int b = 0; b < BINS; ++b) {
            hist[wid * BINS + b]                       = s[b];
            hist[wid * BINS + b + (THREADS / 64) * BINS] = c[b];
        }
    }
    __syncthreads();
    if (tid < BINS) {
        float sb = 0.0f, cb = 0.0f;
#pragma unroll
        for (int w2 = 0; w2 < THREADS / 64; ++w2) {
            sb += hist[w2 * BINS + tid];
            cb += hist[w2 * BINS + tid + (THREADS / 64) * BINS];
        }
        part[blockIdx.x].sum[tid] = sb;
        part[blockIdx.x].cnt[tid] = cb;
    }
}

__global__ __launch_bounds__(THREADS) void ghmc_finalize(const Partial* __restrict__ part,
                                                         float* __restrict__ out,
                                                         int nblocks) {
    double acc[BINS], cn[BINS];
#pragma unroll
    for (int b = 0; b < BINS; ++b) { acc[b] = 0.0; cn[b] = 0.0; }

    const int tid = threadIdx.x;
    for (int i = tid; i < nblocks; i += THREADS) {
#pragma unroll
        for (int b = 0; b < BINS; ++b) {
            acc[b] += (double)part[i].sum[b];
            cn[b]  += (double)part[i].cnt[b];
        }
    }
#pragma unroll
    for (int b = 0; b < BINS; ++b) {
#pragma unroll
        for (int off = 32; off; off >>= 1) {
            acc[b] += __shfl_xor(acc[b], off, 64);
            cn[b]  += __shfl_xor(cn[b], off, 64);
        }
    }

    __shared__ double lds_s[THREADS / 64][BINS];
    __shared__ double lds_c[THREADS / 64][BINS];
    const int wid  = tid >> 6;
    const int lane = tid & 63;
    if (lane == 0) {
#pragma unroll
        for (int b = 0; b < BINS; ++b) { lds_s[wid][b] = acc[b]; lds_c[wid][b] = cn[b]; }
    }
    __syncthreads();

    if (tid == 0) {
        double loss = 0.0;
        int n = 0;
        for (int b = 0; b < BINS; ++b) {
            double sb = 0.0, cb = 0.0;
            for (int w2 = 0; w2 < THREADS / 64; ++w2) { sb += lds_s[w2][b]; cb += lds_c[w2][b]; }
            if (cb > 0.0) { loss += sb / cb; ++n; }
        }
        double denom = (n > 0) ? (double)n : 1.0;
        out[0] = (float)(loss / denom);   // LOSS_WEIGHT == 1.0; tot cancels algebraically
    }
}

extern "C" void kernel_launch(void* const* d_in, const int* in_sizes, int n_in,
                              void* d_out, int out_size, void* d_ws, size_t ws_size,
                              hipStream_t stream) {
    const float* pred   = (const float*)d_in[0];
    const float* target = (const float*)d_in[1];
    const float* lw     = (const float*)d_in[2];
    float* out = (float*)d_out;
    Partial* part = (Partial*)d_ws;
    const long long total = (long long)in_sizes[0];

    ghmc_main<<<NBLOCKS, THREADS, 0, stream>>>(pred, target, lw, part, total);
    ghmc_finalize<<<1, THREADS, 0, stream>>>(part, out, NBLOCKS);
}

// Round 5
// 436.978 us; speedup vs baseline: 1.6544x; 1.6544x over previous
//
#include <hip/hip_runtime.h>
#include <math.h>

#define BINS 10
#define NBLOCKS 2048
#define THREADS 256

// Prefix-form partials: sum[k]/cnt[k] accumulate over elements with g >= k/10
// (i.e. s >= logit(k/10)). Per-bin values recovered in finalize via adjacent diff.
struct Partial {
    float        sum[BINS];
    unsigned int cnt[BINS];
};

// logit(k/10) = ln(k/(10-k)), k=1..9
__device__ __constant__ const float TH[9] = {
    -2.1972245773f, -1.3862943611f, -0.8472978604f, -0.4054651081f, 0.0f,
     0.4054651081f,  0.8472978604f,  1.3862943611f,  2.1972245773f
};

// s = x*(1-2t): g = sigmoid(s), bce = softplus(s) = max(s,0)+log1p(exp(-|s|)).
// Exact identities with the reference's stable-BCE form (|s| == |x|).
__device__ __forceinline__ void accum_one(float x, float t, float w,
                                          float (&A)[BINS], unsigned int (&C)[BINS]) {
    float m2t = -2.0f * t;
    float s   = __builtin_fmaf(m2t, x, x);        // x - 2tx
    float ax  = __builtin_fabsf(x);
    float e   = __expf(-ax);                      // exp(-|s|)
    float lg  = __logf(1.0f + e);
    float bce = fmaxf(s, 0.0f) + lg;
    bool valid = (w > 0.0f);
    bce = valid ? bce : 0.0f;                     // invalid contributes nothing
    float sv = valid ? s : -1e30f;                // fails every threshold
    A[0] += bce;                                  // prefix-0 = all valid
    C[0] += (unsigned int)__popcll(__ballot(valid));
#pragma unroll
    for (int k = 1; k < BINS; ++k) {
        bool m = (sv >= TH[k - 1]);
        A[k] += m ? bce : 0.0f;                   // v_cmp + v_cndmask + v_add
        C[k] += (unsigned int)__popcll(__ballot(m));   // SALU: s_bcnt1 + s_add
    }
}

__device__ __forceinline__ void accum4(const float4& p, const float4& t, const float4& w,
                                       float (&A)[BINS], unsigned int (&C)[BINS]) {
    accum_one(p.x, t.x, w.x, A, C);
    accum_one(p.y, t.y, w.y, A, C);
    accum_one(p.z, t.z, w.z, A, C);
    accum_one(p.w, t.w, w.w, A, C);
}

__global__ __launch_bounds__(THREADS) void ghmc_main(const float* __restrict__ pred,
                                                     const float* __restrict__ target,
                                                     const float* __restrict__ lw,
                                                     Partial* __restrict__ part,
                                                     long long total) {
    float        A[BINS];
    unsigned int C[BINS];
#pragma unroll
    for (int b = 0; b < BINS; ++b) { A[b] = 0.0f; C[b] = 0u; }

    const int tid = threadIdx.x;
    const long long nvec   = total >> 2;
    const long long stride = (long long)gridDim.x * THREADS;
    const float4* __restrict__ P = reinterpret_cast<const float4*>(pred);
    const float4* __restrict__ T = reinterpret_cast<const float4*>(target);
    const float4* __restrict__ W = reinterpret_cast<const float4*>(lw);

    // 1-deep register prefetch: next stride's loads in flight during current compute
    long long i = (long long)blockIdx.x * THREADS + tid;
    const bool have = (i < nvec);
    float4 pa, ta, wa;
    if (have) { pa = P[i]; ta = T[i]; wa = W[i]; }
    for (long long j = i + stride; j < nvec; j += stride) {
        float4 pb = P[j], tb = T[j], wb = W[j];
        accum4(pa, ta, wa, A, C);
        pa = pb; ta = tb; wa = wb;
    }
    if (have) accum4(pa, ta, wa, A, C);

    // scalar tail (total % 4): block 0 only
    const long long base = nvec << 2;
    const int rem = (int)(total - base);
    if (blockIdx.x == 0 && tid < rem)
        accum_one(pred[base + tid], target[base + tid], lw[base + tid], A, C);

    // sums: wave butterfly; counts already wave-uniform (ballot path)
#pragma unroll
    for (int b = 0; b < BINS; ++b) {
#pragma unroll
        for (int off = 32; off; off >>= 1)
            A[b] += __shfl_xor(A[b], off, 64);
    }

    __shared__ float        ls[THREADS / 64][BINS];
    __shared__ unsigned int lc[THREADS / 64][BINS];
    const int wid  = tid >> 6;
    const int lane = tid & 63;
    if (lane == 0) {
#pragma unroll
        for (int b = 0; b < BINS; ++b) { ls[wid][b] = A[b]; lc[wid][b] = C[b]; }
    }
    __syncthreads();

    if (tid < BINS) {
        float sb = 0.0f; unsigned int cb = 0u;
#pragma unroll
        for (int w2 = 0; w2 < THREADS / 64; ++w2) { sb += ls[w2][tid]; cb += lc[w2][tid]; }
        part[blockIdx.x].sum[tid] = sb;   // plain store, no atomics
        part[blockIdx.x].cnt[tid] = cb;
    }
}

__global__ __launch_bounds__(THREADS) void ghmc_finalize(const Partial* __restrict__ part,
                                                         float* __restrict__ out,
                                                         int nblocks) {
    double             acc[BINS];
    unsigned long long cn[BINS];
#pragma unroll
    for (int b = 0; b < BINS; ++b) { acc[b] = 0.0; cn[b] = 0ull; }

    const int tid = threadIdx.x;
    for (int i = tid; i < nblocks; i += THREADS) {
#pragma unroll
        for (int b = 0; b < BINS; ++b) {
            acc[b] += (double)part[i].sum[b];
            cn[b]  += (unsigned long long)part[i].cnt[b];
        }
    }
#pragma unroll
    for (int b = 0; b < BINS; ++b) {
#pragma unroll
        for (int off = 32; off; off >>= 1) {
            acc[b] += __shfl_xor(acc[b], off, 64);
            cn[b]  += __shfl_xor(cn[b], off, 64);
        }
    }

    __shared__ double             lds_s[THREADS / 64][BINS];
    __shared__ unsigned long long lds_c[THREADS / 64][BINS];
    const int wid  = tid >> 6;
    const int lane = tid & 63;
    if (lane == 0) {
#pragma unroll
        for (int b = 0; b < BINS; ++b) { lds_s[wid][b] = acc[b]; lds_c[wid][b] = cn[b]; }
    }
    __syncthreads();

    if (tid == 0) {
        double pS[BINS + 1];
        double pC[BINS + 1];
        for (int b = 0; b < BINS; ++b) {
            double sb = 0.0; unsigned long long cb = 0ull;
            for (int w2 = 0; w2 < THREADS / 64; ++w2) { sb += lds_s[w2][b]; cb += lds_c[w2][b]; }
            pS[b] = sb; pC[b] = (double)cb;
        }
        pS[BINS] = 0.0; pC[BINS] = 0.0;
        double loss = 0.0;
        int n = 0;
        for (int b = 0; b < BINS; ++b) {
            double cb = pC[b] - pC[b + 1];      // prefix -> per-bin
            double sb = pS[b] - pS[b + 1];
            if (cb > 0.0) { loss += sb / cb; ++n; }
        }
        double denom = (n > 0) ? (double)n : 1.0;
        out[0] = (float)(loss / denom);   // LOSS_WEIGHT == 1.0; tot cancels algebraically
    }
}

extern "C" void kernel_launch(void* const* d_in, const int* in_sizes, int n_in,
                              void* d_out, int out_size, void* d_ws, size_t ws_size,
                              hipStream_t stream) {
    const float* pred   = (const float*)d_in[0];
    const float* target = (const float*)d_in[1];
    const float* lw     = (const float*)d_in[2];
    float* out = (float*)d_out;
    Partial* part = (Partial*)d_ws;
    const long long total = (long long)in_sizes[0];

    ghmc_main<<<NBLOCKS, THREADS, 0, stream>>>(pred, target, lw, part, total);
    ghmc_finalize<<<1, THREADS, 0, stream>>>(part, out, NBLOCKS);
}